// Round 9
// baseline (32.772 us; speedup 1.0000x reference)
//
#include <hip/hip_runtime.h>
#include <math.h>

// LightconvLayer: x (T,B,C) f32, weight (H,K) f32 -> out (T,B,C) f32
// out[t,b,c] = sum_k softmax(weight[c/64])[k] * x[t+k-30, b, c] (zero-pad left)
//
// R9: contiguity fix (H3). 4-wave block covers 256 ch -> staging loads are
// 1 KB CONTIGUOUS (width-16 gload_lds = one full ring row per instruction),
// vs R8's 256 B chunks at 32 KB stride (DRAM page locality).
// Pipeline stays R8-style: prefetch-ahead-2, counted OWN-vmcnt per wave
// BEFORE the single per-tile s_barrier (no drain, no __syncthreads).
//  - ring[64][256] f32 = 64 KB -> 2 blocks/CU, 8 waves/CU.
//  - per tile (TT=8): each wave stages 2 rows of tile j+2, waits own
//    vmcnt(20) (steady: S(j-2)8+L(j+1)2+S(j-1)8+L(j+2)2), s_barrier,
//    38 ds_read (2-way bank = free) + 248 FMA w/ SGPR taps, 8 stores.
//  - slot safety: stage(j+2) slots (8jj+16..23)&63 disjoint from window(j)
//    (8jj+34..+71 mod 64) and window(j-1) -> one barrier per tile suffices.
#define T_LEN 2048
#define B_SZ  8
#define C_SZ  1024
#define NH    16
#define KW    31
#define HALO  (KW - 1)        // 30
#define TT    8
#define CHUNK 128             // rows per block (tb % 64 == 0 -> ct slots)
#define NTILE (CHUNK / TT)    // 16
#define RING  64
#define WIN   (TT + HALO)     // 38
#define CG    256             // channels per block
#define ROWSTRIDE (B_SZ * C_SZ)  // 8192 floats between t rows

#define GLOBAL_AS(p) ((const __attribute__((address_space(1))) void*)(p))
#define LDS_AS(p)    ((__attribute__((address_space(3))) void*)(p))

__global__ __launch_bounds__(256, 2) void lightconv_kernel(
    const float* __restrict__ x, const float* __restrict__ weight,
    float* __restrict__ out) {
  __shared__ float ring[RING][CG];   // 64 KB
  const int tid  = threadIdx.x;
  const int w    = tid >> 6;         // wave 0..3
  const int lane = tid & 63;

  const int cg = blockIdx.x & 3;     // 256-ch group
  const int tc = blockIdx.x >> 2;    // t-chunk 0..15
  const int b  = blockIdx.y;
  const int c0 = cg * CG;
  const int tb = tc * CHUNK;         // tb % 64 == 0

  // --- taps: wave = one head (64 ch). uniform loads -> softmax -> SGPR ---
  const int head = cg * 4 + w;
  float wv[KW];
  float m = -1e30f;
#pragma unroll
  for (int k = 0; k < KW; ++k) {
    wv[k] = weight[head * KW + k];   // wave-uniform -> s_load
    m = fmaxf(m, wv[k]);
  }
  float s = 0.f;
#pragma unroll
  for (int k = 0; k < KW; ++k) {
    wv[k] = expf(wv[k] - m);
    s += wv[k];
  }
  const float inv = 1.f / s;
  float wk[KW];
#pragma unroll
  for (int k = 0; k < KW; ++k) {
    wk[k] = __uint_as_float(
        __builtin_amdgcn_readfirstlane(__float_as_uint(wv[k] * inv)));
  }

  // staging: one width-16 gload_lds = 64 lanes x 16 B = full 1 KB row
  const float* xbase = x + (size_t)b * C_SZ + c0;
  const int loff = lane * 4;         // floats: lane covers ch 4*lane..+3

  // --- prologue: stage rows tb-32..tb+7 (wave w: rows w+4*pp) + L(1) ---
  if (tb == 0) {
#pragma unroll
    for (int i = 0; i < 32; ++i) ring[32 + i][tid] = 0.f;  // rows -32..-1
#pragma unroll
    for (int pp = 0; pp < 2; ++pp) {                        // rows 0..7
      const int t = w + 4 * pp;
      const float* gp = xbase + (size_t)t * ROWSTRIDE + loff;
      __builtin_amdgcn_global_load_lds(GLOBAL_AS(gp), LDS_AS(&ring[t][0]),
                                       16, 0, 0);
    }
  } else {
#pragma unroll
    for (int pp = 0; pp < 10; ++pp) {                       // rows tb-32..tb+7
      const int t = tb - 32 + w + 4 * pp;
      const int slot = (32 + w + 4 * pp) & (RING - 1);
      const float* gp = xbase + (size_t)t * ROWSTRIDE + loff;
      __builtin_amdgcn_global_load_lds(GLOBAL_AS(gp), LDS_AS(&ring[slot][0]),
                                       16, 0, 0);
    }
  }
#pragma unroll
  for (int pp = 0; pp < 2; ++pp) {                          // L(1): rows tb+8..15
    const int t = tb + TT + w + 4 * pp;
    const int slot = 8 + w + 4 * pp;
    const float* gp = xbase + (size_t)t * ROWSTRIDE + loff;
    __builtin_amdgcn_global_load_lds(GLOBAL_AS(gp), LDS_AS(&ring[slot][0]),
                                     16, 0, 0);
  }
  // own L(0) drained (keep L(1) in flight); zero-fill ds_writes drained
  asm volatile("s_waitcnt vmcnt(2) lgkmcnt(0)" ::: "memory");
  __builtin_amdgcn_s_barrier();
  __builtin_amdgcn_sched_barrier(0);

  // --- main loop: 16 tiles, one barrier each, counted own-vmcnt ---
#pragma unroll 1
  for (int jo = 0; jo < 2; ++jo) {
#pragma unroll
    for (int jj = 0; jj < NTILE / 2; ++jj) {
      const int j = jo * 8 + jj;
      const int tstart = tb + jo * 64 + jj * TT;

      // stage L(j+2): wave w stages rows tstart+16+w, tstart+20+w
      if (j <= NTILE - 3) {
#pragma unroll
        for (int pp = 0; pp < 2; ++pp) {
          const int t = tstart + 2 * TT + w + 4 * pp;
          const int slot = (8 * jj + 16 + w + 4 * pp) & (RING - 1);
          const float* gp = xbase + (size_t)t * ROWSTRIDE + loff;
          __builtin_amdgcn_global_load_lds(GLOBAL_AS(gp),
                                           LDS_AS(&ring[slot][0]), 16, 0, 0);
        }
      }
      // counted OWN wait (in-order): guarantee own L(j) retired pre-barrier
      if (j == 0)                asm volatile("s_waitcnt vmcnt(4)"  ::: "memory");
      else if (j == 1)           asm volatile("s_waitcnt vmcnt(12)" ::: "memory");
      else if (j == NTILE - 2)   asm volatile("s_waitcnt vmcnt(18)" ::: "memory");
      else if (j == NTILE - 1)   asm volatile("s_waitcnt vmcnt(16)" ::: "memory");
      else                       asm volatile("s_waitcnt vmcnt(20)" ::: "memory");
      __builtin_amdgcn_sched_barrier(0);
      __builtin_amdgcn_s_barrier();       // all waves' L(j) now visible
      __builtin_amdgcn_sched_barrier(0);  // rule #18: pin ds_reads below

      // compute tile j (thread = channel c0 + tid; slot imm offsets)
      float xv[WIN];
#pragma unroll
      for (int i = 0; i < WIN; ++i) {
        xv[i] = ring[(8 * jj + 34 + i) & (RING - 1)][tid];
      }
      float* op = out + ((size_t)tstart * B_SZ + b) * C_SZ + c0 + tid;
#pragma unroll
      for (int o = 0; o < TT; ++o) {
        float a = 0.f;
#pragma unroll
        for (int k = 0; k < KW; ++k) a = fmaf(wk[k], xv[o + k], a);
        op[(size_t)o * ROWSTRIDE] = a;
      }
    }
  }
}

extern "C" void kernel_launch(void* const* d_in, const int* in_sizes, int n_in,
                              void* d_out, int out_size, void* d_ws, size_t ws_size,
                              hipStream_t stream) {
  const float* x = (const float*)d_in[0];      // (T,B,C) f32
  const float* w = (const float*)d_in[1];      // (H,K) f32
  float* out = (float*)d_out;                  // (T,B,C) f32
  (void)in_sizes; (void)n_in; (void)out_size; (void)d_ws; (void)ws_size;

  dim3 grid((C_SZ / CG) * (T_LEN / CHUNK), B_SZ);  // (64, 8) = 512 blocks
  dim3 block(256);
  lightconv_kernel<<<grid, block, 0, stream>>>(x, w, out);
}